// Round 18
// baseline (219.475 us; speedup 1.0000x reference)
//
#include <hip/hip_runtime.h>

#define HD 128   // hidden / feature dim
#define PS 32    // pooling chunks per graph

typedef __bf16 bf16x8 __attribute__((ext_vector_type(8)));
typedef float  f32x16 __attribute__((ext_vector_type(16)));
typedef unsigned short u16x4 __attribute__((ext_vector_type(4)));
typedef _Float16 f16x8 __attribute__((ext_vector_type(8)));

__device__ inline unsigned short f2bf_rne(float f) {
  unsigned u = __builtin_bit_cast(unsigned, f);
  unsigned r = u + 0x7fffu + ((u >> 16) & 1u);
  return (unsigned short)(r >> 16);
}
__device__ inline float bf2f(unsigned short h) {
  unsigned u = ((unsigned)h) << 16;
  return __builtin_bit_cast(float, u);
}
__device__ inline void cvt4(float4 f, u16x4& h, u16x4& l) {
  h[0] = f2bf_rne(f.x); l[0] = f2bf_rne(f.x - bf2f(h[0]));
  h[1] = f2bf_rne(f.y); l[1] = f2bf_rne(f.y - bf2f(h[1]));
  h[2] = f2bf_rne(f.z); l[2] = f2bf_rne(f.z - bf2f(h[2]));
  h[3] = f2bf_rne(f.w); l[3] = f2bf_rne(f.w - bf2f(h[3]));
}

// ---------------- fused prep: xsplit | wsplit | init-cnt + graph sentinels ----------------
__global__ __launch_bounds__(256) void k_prep(const float* __restrict__ x, unsigned short* __restrict__ ph,
                                              unsigned short* __restrict__ pl, int nelem4,
                                              const float* __restrict__ W1, const float* __restrict__ W2,
                                              const float* __restrict__ W3, unsigned short* __restrict__ wimg,
                                              int* __restrict__ cnt, int n, int nbX,
                                              int* __restrict__ gstart, int* __restrict__ gend, int g) {
  int b = blockIdx.x;
  int t = threadIdx.x;
  if (b < nbX) {                       // x -> split-bf16 planes (unscaled)
    int i = b * 256 + t;
    if (i < nelem4) {
      float4 f = ((const float4*)x)[i];
      u16x4 h, l;
      cvt4(f, h, l);
      ((u16x4*)ph)[i] = h;
      ((u16x4*)pl)[i] = l;
    }
  } else if (b < nbX + 51) {           // W split/transpose/pad LDS image
    int wb = b - nbX;
    const float* W = (wb < 17) ? W1 : (wb < 34) ? W2 : W3;
    unsigned short* out = wimg + (size_t)(wb / 17) * 34816;
    int base = ((wb % 17) * 256 + t) * 4;
#pragma unroll
    for (int p = 0; p < 4; ++p) {
      int flat = base + p;             // 0..17407
      int c = flat / 136, j = flat - c * 136;
      float v = (j < 128) ? W[(size_t)j * HD + c] : 0.f;
      unsigned short hi = f2bf_rne(v);
      float lo = (j < 128) ? (v - bf2f(hi)) : 0.f;
      out[(size_t)c * 136 + j] = hi;
      out[17408 + (size_t)c * 136 + j] = f2bf_rne(lo);
    }
  } else {                             // zero in-degree counters (+ sentinels, first block)
    int bb = b - nbX - 51;
    int i = bb * 256 + t;
    if (i < n) cnt[i] = 0;
    if (bb == 0 && t < g) { gstart[t] = 0x7fffffff; gend[t] = -1; }
  }
}

// ---------------- per-block exclusive scan; bsum[b] = block b's total ----------------
__global__ __launch_bounds__(256) void k_scan1(const int* __restrict__ cnt, int* __restrict__ excl,
                                               int* __restrict__ bsum, int n) {
  __shared__ int s[256];
  int tid = threadIdx.x;
  int i = blockIdx.x * 256 + tid;
  int v = (i < n) ? cnt[i] : 0;
  s[tid] = v; __syncthreads();
  for (int off = 1; off < 256; off <<= 1) {
    int t = (tid >= off) ? s[tid - off] : 0;
    __syncthreads();
    s[tid] += t;
    __syncthreads();
  }
  if (i < n) excl[i] = s[tid] - v;
  if (tid == 255) bsum[blockIdx.x] = s[255];
}

// rowptr += prefix(bsum[0..b)); dis = rsqrt(1+deg); graph ranges via sorted-batch
// boundaries. Each block computes its own bsum prefix (<=256 ints, wave 0).
__global__ __launch_bounds__(256) void k_finalize(int* __restrict__ rowptr, const int* __restrict__ bsum,
                                                  const int* __restrict__ cnt, float* __restrict__ dis,
                                                  const int* __restrict__ batch, int* __restrict__ gstart,
                                                  int* __restrict__ gend, int n) {
  __shared__ int spre;
  int tid = threadIdx.x;
  int nb = blockIdx.x;                 // need sum of bsum[0..nb)
  if (tid < 64) {
    int acc = 0;
    for (int j = tid; j < nb; j += 64) acc += bsum[j];
#pragma unroll
    for (int m = 1; m < 64; m <<= 1) acc += __shfl_xor(acc, m);
    if (tid == 0) spre = acc;
  }
  __syncthreads();
  int pre = spre;
  int i = nb * 256 + tid;
  if (i >= n) return;
  rowptr[i] += pre;
  dis[i] = rsqrtf(1.0f + (float)cnt[i]);
  int b = batch[i];
  if (i == 0 || batch[i - 1] != b) gstart[b] = i;
  if (i == n - 1 || batch[i + 1] != b) gend[b] = i;
}

// ---------------- CSR fill (atomic-free) ----------------
__global__ __launch_bounds__(256) void k_fill(const int* __restrict__ src, const int* __restrict__ dst,
                                              const int* __restrict__ rowptr, const int* __restrict__ eslot,
                                              int* __restrict__ csr, int e) {
  int i = blockIdx.x * 256 + threadIdx.x;
  if (i >= e) return;
  csr[rowptr[dst[i]] + eslot[i]] = src[i];
}

// ---------------- split-bf16 MFMA GEMM, single K=128 tile, one barrier, 16 waves ----------
// A pre-split (hi/lo ushort planes, row-scale pre-folded by producer); C = A@W in fp16.
// Optional tail (layer 1): in-degree histogram — atomic wall overlaps staging/MFMA.
__global__ __launch_bounds__(1024) void k_gemm(const unsigned short* __restrict__ AH,
                                               const unsigned short* __restrict__ AL,
                                               const unsigned short* __restrict__ wimg_l,
                                               _Float16* __restrict__ C, int M,
                                               const int* __restrict__ hdst, int* __restrict__ hcnt,
                                               int* __restrict__ heslot, int hE) {
  __shared__ unsigned short alds[2][128][136];   // 69632 B
  __shared__ unsigned short wlds[2][128][136];   // 69632 B
  int t = threadIdx.x;
  int row0 = blockIdx.x * 128;
  char* ab = (char*)alds;
  char* wb = (char*)wlds;
  const int PL = 128 * 272;

  // stage A: 2 planes x 2048 float4 slots (coalesced), dest padded rows
  {
    const float4* sH = (const float4*)(AH + (size_t)row0 * HD);
    const float4* sL = (const float4*)(AL + (size_t)row0 * HD);
#pragma unroll
    for (int u = 0; u < 2; ++u) {
      int s = u * 1024 + t;              // 0..2047
      int r = s >> 4, c = s & 15;
      *(float4*)(ab + r * 272 + c * 16) = sH[s];
      *(float4*)(ab + PL + r * 272 + c * 16) = sL[s];
    }
  }
  // stage W: linear copy of pre-formatted image (4352 float4)
  {
    const float4* sW = (const float4*)wimg_l;
    float4* dW = (float4*)wb;
#pragma unroll
    for (int u = 0; u < 4; ++u) dW[u * 1024 + t] = sW[u * 1024 + t];
    if (t < 256) dW[4096 + t] = sW[4096 + t];
  }
  __syncthreads();

  int w = t >> 6, lane = t & 63;
  int l31 = lane & 31, lhi = lane >> 5;
  int wr = (w >> 2) * 32, wc = (w & 3) * 32;

  f32x16 acc;
#pragma unroll
  for (int i = 0; i < 16; ++i) acc[i] = 0.f;

#pragma unroll
  for (int ks = 0; ks < 8; ++ks) {
    int ko = ks * 32 + lhi * 16;
    bf16x8 ah = *(const bf16x8*)(ab + (wr + l31) * 272 + ko);
    bf16x8 al = *(const bf16x8*)(ab + PL + (wr + l31) * 272 + ko);
    bf16x8 bh = *(const bf16x8*)(wb + (wc + l31) * 272 + ko);
    bf16x8 bl = *(const bf16x8*)(wb + PL + (wc + l31) * 272 + ko);
    acc = __builtin_amdgcn_mfma_f32_32x32x16_bf16(ah, bh, acc, 0, 0, 0);
    acc = __builtin_amdgcn_mfma_f32_32x32x16_bf16(ah, bl, acc, 0, 0, 0);
    acc = __builtin_amdgcn_mfma_f32_32x32x16_bf16(al, bh, acc, 0, 0, 0);
  }

  // epilogue: C/D layout col = lane&31, row = (r&3) + 8*(r>>2) + 4*lhi; fp16 store
  int col = wc + l31;
  int rbase = row0 + wr + 4 * lhi;
#pragma unroll
  for (int r = 0; r < 16; ++r) {
    int row = rbase + (r & 3) + 8 * (r >> 2);
    if (row < M) C[(size_t)row * HD + col] = (_Float16)acc[r];
  }

  // tail: histogram chunk (no LDS, no barrier — waves proceed independently)
  if (hdst) {
    int stride = gridDim.x * 1024;
    for (int i = blockIdx.x * 1024 + t; i < hE; i += stride)
      heslot[i] = atomicAdd(&hcnt[hdst[i]], 1);
  }
}

// ---------------- gather aggregation + self loop + bias + relu ----------------
// 16-LANE-GROUP per node: lane reads 8 channels (f16x8, 16B); a group's 16 lanes
// cover one 256B row (coalesced). 4 groups/wave = 4 independent csr chains,
// 4 streams each -> 16 rows in flight per wave (vs 8 in the half-wave form).
// L1: C unscaled -> apply dis[src] per edge, dn on self. Plane path folds dn.
template <bool L1>
__global__ __launch_bounds__(256) void k_gather(const _Float16* __restrict__ C, const float* __restrict__ dis,
                                                const int* __restrict__ rowptr, const int* __restrict__ cnt,
                                                const int* __restrict__ csr, const float* __restrict__ bias,
                                                float* __restrict__ outF, unsigned short* __restrict__ outH,
                                                unsigned short* __restrict__ outL, int n) {
  int lane = threadIdx.x & 63;
  int wid = threadIdx.x >> 6;
  int grp = lane >> 4;                 // 0..3
  int l16 = lane & 15;
  int node = blockIdx.x * 16 + wid * 4 + grp;
  if (node >= n) return;
  int coff = l16 * 8;                  // this lane's 8 channels
  int s = rowptr[node];
  int deg = cnt[node];

  float dn = dis[node];
  f16x8 sh8 = *(const f16x8*)(C + (size_t)node * HD + coff);
  float bb[8];
  *(float4*)&bb[0] = *(const float4*)(bias + coff);
  *(float4*)&bb[4] = *(const float4*)(bias + coff + 4);

  float a0[8], a1[8], a2[8], a3[8];
#pragma unroll
  for (int j = 0; j < 8; ++j) { a0[j] = 0.f; a1[j] = 0.f; a2[j] = 0.f; a3[j] = 0.f; }

  int i = 0;
  for (; i + 4 <= deg; i += 4) {          // 4 independent row streams per group
    int i0 = csr[s + i];
    int i1 = csr[s + i + 1];
    int i2 = csr[s + i + 2];
    int i3 = csr[s + i + 3];
    f16x8 v0 = *(const f16x8*)(C + (size_t)i0 * HD + coff);
    f16x8 v1 = *(const f16x8*)(C + (size_t)i1 * HD + coff);
    f16x8 v2 = *(const f16x8*)(C + (size_t)i2 * HD + coff);
    f16x8 v3 = *(const f16x8*)(C + (size_t)i3 * HD + coff);
    float w0 = 1.f, w1 = 1.f, w2 = 1.f, w3 = 1.f;
    if (L1) { w0 = dis[i0]; w1 = dis[i1]; w2 = dis[i2]; w3 = dis[i3]; }
#pragma unroll
    for (int j = 0; j < 8; ++j) {
      a0[j] += w0 * (float)v0[j];
      a1[j] += w1 * (float)v1[j];
      a2[j] += w2 * (float)v2[j];
      a3[j] += w3 * (float)v3[j];
    }
  }
  for (; i < deg; ++i) {                  // tail (up to 3)
    int i0 = csr[s + i];
    f16x8 v0 = *(const f16x8*)(C + (size_t)i0 * HD + coff);
    float w0 = L1 ? dis[i0] : 1.f;
#pragma unroll
    for (int j = 0; j < 8; ++j) a0[j] += w0 * (float)v0[j];
  }
#pragma unroll
  for (int j = 0; j < 8; ++j) a0[j] += a1[j] + a2[j] + a3[j];

  float ss = L1 ? dn : 1.f;               // self term scale
  float r[8];
#pragma unroll
  for (int j = 0; j < 8; ++j)
    r[j] = fmaxf(dn * (a0[j] + ss * (float)sh8[j]) + bb[j], 0.f);

  if (outF) {
    *(float4*)(outF + (size_t)node * HD + coff)     = *(float4*)&r[0];
    *(float4*)(outF + (size_t)node * HD + coff + 4) = *(float4*)&r[4];
  } else {
    // planes feed the next gemm: store dis[node]*h[node] (rowscale pre-folded)
    float4 rs0 = make_float4(dn * r[0], dn * r[1], dn * r[2], dn * r[3]);
    float4 rs1 = make_float4(dn * r[4], dn * r[5], dn * r[6], dn * r[7]);
    u16x4 h0, l0, h1, l1;
    cvt4(rs0, h0, l0);
    cvt4(rs1, h1, l1);
    *(u16x4*)(outH + (size_t)node * HD + coff)     = h0;
    *(u16x4*)(outH + (size_t)node * HD + coff + 4) = h1;
    *(u16x4*)(outL + (size_t)node * HD + coff)     = l0;
    *(u16x4*)(outL + (size_t)node * HD + coff + 4) = l1;
  }
}

// ---------------- pooling stage 1 ----------------
__global__ __launch_bounds__(128) void k_pool1(const float* __restrict__ h, const int* __restrict__ gstart,
                                               const int* __restrict__ gend, float* __restrict__ psum,
                                               float* __restrict__ pmax) {
  int g = blockIdx.x, sidx = blockIdx.y, c = threadIdx.x;
  int s = gstart[g], e = gend[g];
  float sum = 0.f, mx = 0.f;
  if (s <= e) {
    int len = e - s + 1;
    int c0 = s + (int)(((long long)len * sidx) / PS);
    int c1 = s + (int)(((long long)len * (sidx + 1)) / PS);
    for (int i = c0; i < c1; ++i) {
      float v = h[(size_t)i * HD + c];
      sum += v;
      mx = fmaxf(mx, v);
    }
  }
  size_t o = ((size_t)g * PS + sidx) * HD + c;
  psum[o] = sum;
  pmax[o] = mx;
}

// ---------------- pooling stage 2 fused with MLP ----------------
__global__ __launch_bounds__(128) void k_pool2mlp(const float* __restrict__ psum, const float* __restrict__ pmax,
                                                  const int* __restrict__ gstart, const int* __restrict__ gend,
                                                  const float* __restrict__ Wf1, const float* __restrict__ bf1,
                                                  const float* __restrict__ Wf2, const float* __restrict__ bf2,
                                                  float* __restrict__ out) {
  __shared__ float p[256];
  __shared__ float red[128];
  int g = blockIdx.x, t = threadIdx.x;
  float sum = 0.f, mx = 0.f;
  for (int sidx = 0; sidx < PS; ++sidx) {
    size_t o = ((size_t)g * PS + sidx) * HD + t;
    sum += psum[o];
    mx = fmaxf(mx, pmax[o]);
  }
  int s = gstart[g], e = gend[g];
  float cntf = (s <= e) ? (float)(e - s + 1) : 1.0f;
  p[t] = sum / cntf;
  p[t + 128] = mx;
  __syncthreads();
  float acc = bf1[t];
  for (int k = 0; k < 256; ++k) acc += p[k] * Wf1[k * HD + t];
  float hv = fmaxf(acc, 0.f);
  red[t] = hv * Wf2[t];
  __syncthreads();
  for (int off = 64; off > 0; off >>= 1) {
    if (t < off) red[t] += red[t + off];
    __syncthreads();
  }
  if (t == 0) out[g] = red[0] + bf2[0];
}

extern "C" void kernel_launch(void* const* d_in, const int* in_sizes, int n_in,
                              void* d_out, int out_size, void* d_ws, size_t ws_size,
                              hipStream_t stream) {
  const float* x   = (const float*)d_in[0];
  const int*   ei  = (const int*)d_in[1];
  const int*   bat = (const int*)d_in[2];
  const float* W1  = (const float*)d_in[3];
  const float* b1  = (const float*)d_in[4];
  const float* W2  = (const float*)d_in[5];
  const float* b2  = (const float*)d_in[6];
  const float* W3  = (const float*)d_in[7];
  const float* b3  = (const float*)d_in[8];
  const float* Wf1 = (const float*)d_in[9];
  const float* bf1 = (const float*)d_in[10];
  const float* Wf2 = (const float*)d_in[11];
  const float* bf2 = (const float*)d_in[12];

  int N = in_sizes[0] / HD;
  int E = in_sizes[1] / 2;
  int G = out_size;

  int gb = (N + 127) / 128;      // gemm blocks
  int Rpad = gb * 128;           // padded row count

  char* w = (char*)d_ws;
  size_t off = 0;
  auto alloc = [&](size_t bytes) -> void* {
    void* p = w + off;
    off = (off + bytes + 255) & ~(size_t)255;
    return p;
  };
  unsigned short* pH0 = (unsigned short*)alloc((size_t)Rpad * HD * 2);
  unsigned short* pL0 = (unsigned short*)alloc((size_t)Rpad * HD * 2);
  unsigned short* pH1 = (unsigned short*)alloc((size_t)Rpad * HD * 2);
  unsigned short* pL1 = (unsigned short*)alloc((size_t)Rpad * HD * 2);
  _Float16* Cbuf = (_Float16*)alloc((size_t)Rpad * HD * 2);
  float* Hf     = (float*)alloc((size_t)N * HD * 4);
  int*   csr    = (int*)alloc((size_t)E * 4);
  int*   cnt    = (int*)alloc((size_t)N * 4);
  int*   rowptr = (int*)alloc((size_t)N * 4);
  float* dis    = (float*)alloc((size_t)N * 4);
  int*   bsum   = (int*)alloc(256 * 4);
  int*   gstart = (int*)alloc((size_t)G * 4);
  int*   gend   = (int*)alloc((size_t)G * 4);
  float* psum   = (float*)alloc((size_t)G * PS * HD * 4);
  float* pmax   = (float*)alloc((size_t)G * PS * HD * 4);
  unsigned short* wimg = (unsigned short*)alloc((size_t)3 * 34816 * 2);
  int*   eslot  = (int*)Hf;      // alias: eslot dead (after k_fill) before gather3 writes Hf

  int nbN = (N + 255) / 256;
  int nbE = (E + 255) / 256;
  int nelem4 = N * HD / 4;
  int nbX = (nelem4 + 255) / 256;

  k_prep<<<nbX + 51 + nbN, 256, 0, stream>>>(x, pH0, pL0, nelem4, W1, W2, W3, wimg, cnt, N, nbX,
                                             gstart, gend, G);
  // gemm layer 1 (UNSCALED C — no dis dependency) + histogram tail (overlapped)
  k_gemm<<<gb, 1024, 0, stream>>>(pH0, pL0, wimg, Cbuf, N, ei + E, cnt, eslot, E);
  k_scan1<<<nbN, 256, 0, stream>>>(cnt, rowptr, bsum, N);
  k_finalize<<<nbN, 256, 0, stream>>>(rowptr, bsum, cnt, dis, bat, gstart, gend, N);
  k_fill<<<nbE, 256, 0, stream>>>(ei, ei + E, rowptr, eslot, csr, E);

  int ab = (N + 15) / 16;
  k_gather<true><<<ab, 256, 0, stream>>>(Cbuf, dis, rowptr, cnt, csr, b1, nullptr, pH1, pL1, N);
  k_gemm<<<gb, 1024, 0, stream>>>(pH1, pL1, wimg + 34816, Cbuf, N, nullptr, nullptr, nullptr, 0);
  k_gather<false><<<ab, 256, 0, stream>>>(Cbuf, dis, rowptr, cnt, csr, b2, nullptr, pH0, pL0, N);
  k_gemm<<<gb, 1024, 0, stream>>>(pH0, pL0, wimg + 69632, Cbuf, N, nullptr, nullptr, nullptr, 0);
  k_gather<false><<<ab, 256, 0, stream>>>(Cbuf, dis, rowptr, cnt, csr, b3, Hf, nullptr, nullptr, N);

  dim3 pgrid(G, PS);
  k_pool1<<<pgrid, 128, 0, stream>>>(Hf, gstart, gend, psum, pmax);
  k_pool2mlp<<<G, 128, 0, stream>>>(psum, pmax, gstart, gend, Wf1, bf1, Wf2, bf2, (float*)d_out);
}